// Round 1
// baseline (651.100 us; speedup 1.0000x reference)
//
#include <hip/hip_runtime.h>
#include <hip/hip_bf16.h>

// Problem: B=2048 batch rows; per row: X[64][768] -> MLP score -> softmax(64) -> w^T X.
// Fused one-block-per-b kernel. X staged in LDS as truncated-bf16 hi + 8-bit mantissa
// extension (fp24-exact reconstruction for the fp32 pooling); GEMM via bf16 MFMA.

#define NINS 64
#define DIM  768
#define NH   64
#define LDX  776   // padded row stride (u16 / u8 units): 776*4B-banks spreads b128 reads

typedef __attribute__((ext_vector_type(8))) short short8;
typedef __attribute__((ext_vector_type(4))) float f32x4;

__device__ __forceinline__ float rec24(ushort hi, unsigned char mid) {
    return __uint_as_float(((unsigned)hi << 16) | ((unsigned)mid << 8));
}

// Prepass: W1bT[h][k] = bf16_rne(W1[768+k][h]); 64x768 u16 = 96 KB into d_ws.
__global__ void prep_w1bt_kernel(const float* __restrict__ W1, ushort* __restrict__ W1bT) {
    int idx = blockIdx.x * blockDim.x + threadIdx.x;
    if (idx >= NH * DIM) return;
    int h = idx / DIM, k = idx - h * DIM;
    unsigned u = __float_as_uint(W1[(size_t)(DIM + k) * NH + h]);
    unsigned r = (u + 0x7FFFu + ((u >> 16) & 1u)) >> 16;   // round-to-nearest-even
    W1bT[h * DIM + k] = (ushort)r;
}

__global__ __launch_bounds__(1024) void attn_pool_kernel(
    const float* __restrict__ inputs, const float* __restrict__ claims,
    const float* __restrict__ W1, const float* __restrict__ b1,
    const float* __restrict__ W2, const float* __restrict__ b2,
    const int* __restrict__ idxp, const ushort* __restrict__ W1bT,
    float* __restrict__ out)
{
    __shared__ ushort        Xhi[NINS][LDX];   // 99,328 B  truncated bf16 of X
    __shared__ unsigned char Xmid[NINS][LDX];  // 49,664 B  next 8 mantissa bits
    __shared__ float         red[16][NH];      //  4,096 B  own-dot partials
    __shared__ float         cOwn[NH];         //    256 B  own*W1a + b1
    __shared__ float         attBuf[4][NINS];  //  1,024 B  per-htile att partials
    __shared__ float         wSm[NINS];        //    256 B  softmax weights
    // total 154,624 B < 160 KiB

    const int t    = threadIdx.x;
    const int b    = blockIdx.x;
    const int lane = t & 63;
    const int w    = t >> 6;          // wave id 0..15
    const int idx  = *idxp;

    const float* xb = inputs + (size_t)b * NINS * DIM;

    // ---- Phase 0a: load X (fp32, coalesced float4) -> split hi16/mid8 into LDS ----
    // 64*192 = 12288 float4 per block, 12 per thread.
    #pragma unroll
    for (int i = 0; i < 12; ++i) {
        int e  = i * 1024 + t;
        int n  = e / (DIM / 4);
        int c4 = e - n * (DIM / 4);
        int d  = c4 * 4;
        const float4 v = *(const float4*)(xb + (size_t)n * DIM + d);
        unsigned u0 = __float_as_uint(v.x), u1 = __float_as_uint(v.y);
        unsigned u2 = __float_as_uint(v.z), u3 = __float_as_uint(v.w);
        ushort4 hi;
        hi.x = (ushort)(u0 >> 16); hi.y = (ushort)(u1 >> 16);
        hi.z = (ushort)(u2 >> 16); hi.w = (ushort)(u3 >> 16);
        uchar4 mid;
        mid.x = (unsigned char)(u0 >> 8); mid.y = (unsigned char)(u1 >> 8);
        mid.z = (unsigned char)(u2 >> 8); mid.w = (unsigned char)(u3 >> 8);
        *(ushort4*)&Xhi[n][d]  = hi;
        *(uchar4*)&Xmid[n][d]  = mid;
    }

    // ---- Phase 0b: own-dot partials (global reads only, overlaps the X load) ----
    // c[h] = dot(own, W1a[:,h]);  t = part*64 + h, 16 parts x 48 d each.
    {
        const float* ownp = (idx >= 0) ? (xb + (size_t)idx * DIM)
                                       : (claims + (size_t)b * DIM);
        const int h = lane, part = w;
        const float* wp = W1 + (size_t)(part * 48) * NH + h;  // W1a rows, coalesced over h
        const float* op = ownp + part * 48;                   // broadcast across lanes
        float s = 0.f;
        #pragma unroll 8
        for (int j = 0; j < 48; ++j) s = fmaf(op[j], wp[(size_t)j * NH], s);
        red[part][h] = s;
    }
    __syncthreads();

    if (t < NH) {
        float s = 0.f;
        #pragma unroll
        for (int p = 0; p < 16; ++p) s += red[p][t];
        cOwn[t] = s + b1[t];
    }
    // (cOwn consumed only after the post-GEMM barrier)

    // ---- Phase 1: S = X * W1b via MFMA. wave w -> tile (mt = w&3 rows, ht = w>>2 cols) ----
    const int mt = w & 3, ht = w >> 2;
    f32x4 acc = {0.f, 0.f, 0.f, 0.f};
    {
        const int ar = mt * 16 + (lane & 15);        // A row
        const int kg = (lane >> 4) * 8;              // k sub-group
        const ushort* ap = &Xhi[ar][kg];
        const ushort* bp = W1bT + (size_t)(ht * 16 + (lane & 15)) * DIM + kg;
        #pragma unroll 4
        for (int kk = 0; kk < 24; ++kk) {
            short8 af = *(const short8*)(ap + kk * 32);
            short8 bf = *(const short8*)(bp + kk * 32);
            acc = __builtin_amdgcn_mfma_f32_16x16x32_bf16(af, bf, acc, 0, 0, 0);
        }
    }
    __syncthreads();   // cOwn now visible to all waves

    // ---- Phase 2: att partials: relu(S + c)*W2, reduce over this tile's 16 h ----
    {
        const int hcol = ht * 16 + (lane & 15);
        const float c  = cOwn[hcol];
        const float w2 = W2[hcol];
        float v[4];
        #pragma unroll
        for (int r = 0; r < 4; ++r)
            v[r] = fmaxf(acc[r] + c, 0.f) * w2;
        #pragma unroll
        for (int r = 0; r < 4; ++r) {
            v[r] += __shfl_xor(v[r], 1, 64);
            v[r] += __shfl_xor(v[r], 2, 64);
            v[r] += __shfl_xor(v[r], 4, 64);
            v[r] += __shfl_xor(v[r], 8, 64);
        }
        if ((lane & 15) == 0) {
            int rbase = mt * 16 + (lane >> 4) * 4;
            #pragma unroll
            for (int r = 0; r < 4; ++r) attBuf[ht][rbase + r] = v[r];
        }
    }
    __syncthreads();

    // ---- Phase 3: softmax over 64 instances (wave 0) ----
    if (t < NINS) {
        float a = attBuf[0][t] + attBuf[1][t] + attBuf[2][t] + attBuf[3][t] + b2[0];
        float m = a;
        #pragma unroll
        for (int mask = 32; mask >= 1; mask >>= 1)
            m = fmaxf(m, __shfl_xor(m, mask, 64));
        float e = __expf(a - m);
        float s = e;
        #pragma unroll
        for (int mask = 32; mask >= 1; mask >>= 1)
            s += __shfl_xor(s, mask, 64);
        wSm[t] = e / s;
    }
    __syncthreads();

    // ---- Phase 4: pooling out[d] = sum_n w[n] * X[n][d] (fp24 reconstruction) ----
    if (t < DIM) {
        float a = 0.f;
        #pragma unroll 8
        for (int n = 0; n < NINS; ++n)
            a = fmaf(wSm[n], rec24(Xhi[n][t], Xmid[n][t]), a);
        out[(size_t)b * DIM + t] = a;
    }
}

extern "C" void kernel_launch(void* const* d_in, const int* in_sizes, int n_in,
                              void* d_out, int out_size, void* d_ws, size_t ws_size,
                              hipStream_t stream)
{
    const float* inputs = (const float*)d_in[0];
    const float* claims = (const float*)d_in[1];
    const float* W1     = (const float*)d_in[2];
    const float* b1     = (const float*)d_in[3];
    const float* W2     = (const float*)d_in[4];
    const float* b2     = (const float*)d_in[5];
    const int*   idxp   = (const int*)d_in[6];
    float*       outp   = (float*)d_out;
    ushort*      W1bT   = (ushort*)d_ws;   // 96 KB scratch, rebuilt every launch

    prep_w1bt_kernel<<<(NH * DIM + 1023) / 1024, 1024, 0, stream>>>(W1, W1bT);
    attn_pool_kernel<<<2048, 1024, 0, stream>>>(inputs, claims, W1, b1, W2, b2,
                                                idxp, W1bT, outp);
}